// Round 6
// baseline (187.035 us; speedup 1.0000x reference)
//
#include <hip/hip_runtime.h>
#include <math.h>

#define T_LEN 4096
#define M_LEN 2048   // complex length after real-packing
#define V_DIM 32
#define B_DIM 128
#define NTHREADS 256

// insert m into descending triple (a0 >= a1 >= a2)
__device__ __forceinline__ void ins3(float& a0, float& a1, float& a2, float m) {
    if (m > a0) { a2 = a1; a1 = a0; a0 = m; }
    else if (m > a1) { a2 = a1; a1 = m; }
    else if (m > a2) { a2 = m; }
}

template <typename Op>
__device__ __forceinline__ void block_reduce2(float& a, float& b, float* scr, Op op) {
    #pragma unroll
    for (int o = 32; o > 0; o >>= 1) {
        a = op(a, __shfl_down(a, o));
        b = op(b, __shfl_down(b, o));
    }
    int lane = threadIdx.x & 63, w = threadIdx.x >> 6;
    if (lane == 0) { scr[w * 2] = a; scr[w * 2 + 1] = b; }
    __syncthreads();
    if (threadIdx.x == 0) {
        float ra = scr[0], rb = scr[1];
        #pragma unroll
        for (int i = 1; i < 4; i++) { ra = op(ra, scr[i * 2]); rb = op(rb, scr[i * 2 + 1]); }
        scr[8] = ra; scr[9] = rb;
    }
    __syncthreads();
    a = scr[8]; b = scr[9];
    __syncthreads();
}

__device__ __forceinline__ void block_reduce_sum20(float* v, float* scr) {
    #pragma unroll
    for (int r = 0; r < 20; r++) {
        #pragma unroll
        for (int o = 32; o > 0; o >>= 1) v[r] += __shfl_down(v[r], o);
    }
    int lane = threadIdx.x & 63, w = threadIdx.x >> 6;
    if (lane == 0) {
        #pragma unroll
        for (int r = 0; r < 20; r++) scr[w * 20 + r] = v[r];
    }
    __syncthreads();
    if (threadIdx.x < 20) {
        float s = scr[threadIdx.x] + scr[20 + threadIdx.x] + scr[40 + threadIdx.x] + scr[60 + threadIdx.x];
        scr[80 + threadIdx.x] = s;
    }
    __syncthreads();
    #pragma unroll
    for (int r = 0; r < 20; r++) v[r] = scr[80 + r];
    __syncthreads();
}

__global__ __launch_bounds__(NTHREADS)
void ts_feat_kernel(const float* __restrict__ x, float* __restrict__ feats) {
    __shared__ __align__(16) float data[2][T_LEN];   // 32 KB; also FFT buffer (float2 view)
    __shared__ float scr[128];

    const int tid = threadIdx.x;
    const int bid = blockIdx.x;            // 0..2047
    const int b  = bid >> 4;               // batch index
    const int v0 = (bid & 15) * 2;         // first variable of the pair

    const float2* __restrict__ p2 =
        reinterpret_cast<const float2*>(x + (size_t)b * T_LEN * V_DIM + v0);

    // ---------- sweep 1: load + sum/min/max ----------
    float s0 = 0.f, s1 = 0.f;
    float mn0 = 3.4e38f, mn1 = 3.4e38f, mx0 = -3.4e38f, mx1 = -3.4e38f;
    #pragma unroll
    for (int i = 0; i < 16; i++) {
        int t = tid + (i << 8);
        float2 val = p2[(size_t)t * (V_DIM / 2)];
        data[0][t] = val.x; data[1][t] = val.y;
        s0 += val.x; s1 += val.y;
        mn0 = fminf(mn0, val.x); mn1 = fminf(mn1, val.y);
        mx0 = fmaxf(mx0, val.x); mx1 = fmaxf(mx1, val.y);
    }
    __syncthreads();
    block_reduce2(s0, s1, scr, [](float a, float c) { return a + c; });
    block_reduce2(mn0, mn1, scr, [](float a, float c) { return fminf(a, c); });
    block_reduce2(mx0, mx1, scr, [](float a, float c) { return fmaxf(a, c); });

    const float mean0 = s0 * (1.f / T_LEN);
    const float mean1 = s1 * (1.f / T_LEN);

    // ---------- sweep 2: centered moments, slope, ACF ----------
    // acc layout per series si (base si*10): [c2, c3, c4, ctc, lag1..lag6]
    float acc[20];
    #pragma unroll
    for (int r = 0; r < 20; r++) acc[r] = 0.f;

    #pragma unroll
    for (int si = 0; si < 2; si++) {
        const float m = si ? mean1 : mean0;
        for (int i = 0; i < 16; i++) {
            int t = tid + (i << 8);
            float xc = data[si][t] - m;
            float xc2 = xc * xc;
            acc[si * 10 + 0] += xc2;
            acc[si * 10 + 1] += xc2 * xc;
            acc[si * 10 + 2] += xc2 * xc2;
            acc[si * 10 + 3] += xc * ((float)t - 2047.5f);
            #pragma unroll
            for (int lag = 1; lag <= 6; lag++) {
                if (t + lag < T_LEN) {
                    acc[si * 10 + 3 + lag] += xc * (data[si][t + lag] - m);
                }
            }
        }
    }
    block_reduce_sum20(acc, scr);

    if (tid == 0) {
        #pragma unroll
        for (int si = 0; si < 2; si++) {
            const float m  = si ? mean1 : mean0;
            const float c2 = acc[si * 10 + 0];
            const float c3 = acc[si * 10 + 1];
            const float c4 = acc[si * 10 + 2];
            const float ct = acc[si * 10 + 3];
            float var = c2 * (1.f / T_LEN);
            float sd  = sqrtf(var + 1e-8f);
            float i3  = 1.f / (sd * sd * sd);
            float skew = c3 * (1.f / T_LEN) * i3;
            float kurt = c4 * (1.f / T_LEN) * i3 / sd;
            float slope = ct / 5726622720.f;      // sum(tc^2) = T(T^2-1)/12
            float dn = c2 + 1e-8f;
            float* fp = feats + (size_t)(bid * 2 + si) * 16;
            fp[0] = m; fp[1] = sd; fp[2] = skew; fp[3] = kurt;
            fp[4] = si ? mn1 : mn0;
            fp[5] = si ? mx1 : mx0;
            fp[6] = slope;
            fp[10] = acc[si * 10 + 4] / dn;
            fp[11] = acc[si * 10 + 5] / dn;
            fp[12] = acc[si * 10 + 6] / dn;
            fp[13] = acc[si * 10 + 7] / dn;
            fp[14] = acc[si * 10 + 8] / dn;
            fp[15] = acc[si * 10 + 9] / dn;
        }
    }

    // ---------- in-place packed-real FFT (radix-2 DIF, M=2048 complex per series) ----------
    float2* Z = reinterpret_cast<float2*>(&data[0][0]);  // series si at Z + si*M_LEN

    for (int s = 10; s >= 0; s--) {
        int half = 1 << s;
        float npih = -3.14159265358979f / (float)half;
        __syncthreads();
        #pragma unroll
        for (int i = 0; i < 8; i++) {
            int bf = tid + (i << 8);            // 0..2047: 1024 butterflies x 2 series
            int si = bf >> 10;
            int q  = bf & 1023;
            int j  = q & (half - 1);
            int i0 = ((q >> s) << (s + 1)) + j + si * M_LEN;
            int i1 = i0 + half;
            float2 a = Z[i0], c = Z[i1];
            float2 sum = make_float2(a.x + c.x, a.y + c.y);
            float2 dif = make_float2(a.x - c.x, a.y - c.y);
            float sn, cs;
            __sincosf(npih * (float)j, &sn, &cs);
            Z[i0] = sum;
            Z[i1] = make_float2(dif.x * cs - dif.y * sn, dif.x * sn + dif.y * cs);
        }
    }
    __syncthreads();

    // ---------- magnitudes (real-unpack) + top-3 ----------
    const float inv_T = 1.f / (float)T_LEN;
    #pragma unroll 1
    for (int si = 0; si < 2; si++) {
        const float2* Zs = Z + si * M_LEN;
        float a0 = -1.f, a1 = -1.f, a2 = -1.f;
        #pragma unroll
        for (int i = 0; i < 8; i++) {
            int k  = 1 + tid + (i << 8);        // 1..2048
            int ka = k & (M_LEN - 1);
            int kb = (M_LEN - k) & (M_LEN - 1);
            float2 Za = Zs[__brev((unsigned)ka) >> 21];
            float2 Zb = Zs[__brev((unsigned)kb) >> 21];
            float Er = 0.5f * (Za.x + Zb.x);
            float Ei = 0.5f * (Za.y - Zb.y);
            float Or = 0.5f * (Za.y + Zb.y);
            float Oi = 0.5f * (Zb.x - Za.x);
            float ang = (float)k * (-3.14159265358979f / (float)M_LEN);
            float sn, cs; __sincosf(ang, &sn, &cs);
            float Xr = Er + cs * Or - sn * Oi;
            float Xi = Ei + cs * Oi + sn * Or;
            float mag = sqrtf(Xr * Xr + Xi * Xi);
            ins3(a0, a1, a2, mag);
        }
        // wave-level merge (lane0 cone uses only valid pulls)
        #pragma unroll
        for (int o = 32; o > 0; o >>= 1) {
            float b0 = __shfl_down(a0, o), b1 = __shfl_down(a1, o), b2 = __shfl_down(a2, o);
            ins3(a0, a1, a2, b0); ins3(a0, a1, a2, b1); ins3(a0, a1, a2, b2);
        }
        int lane = tid & 63, w = tid >> 6;
        if (lane == 0) { scr[w * 3 + 0] = a0; scr[w * 3 + 1] = a1; scr[w * 3 + 2] = a2; }
        __syncthreads();
        if (tid == 0) {
            float t0 = scr[0], t1 = scr[1], t2 = scr[2];
            #pragma unroll
            for (int w2 = 1; w2 < 4; w2++) {
                ins3(t0, t1, t2, scr[w2 * 3 + 0]);
                ins3(t0, t1, t2, scr[w2 * 3 + 1]);
                ins3(t0, t1, t2, scr[w2 * 3 + 2]);
            }
            float* fp = feats + (size_t)(bid * 2 + si) * 16;
            fp[7] = t0 * inv_T; fp[8] = t1 * inv_T; fp[9] = t2 * inv_T;
        }
        __syncthreads();
    }
}

__global__ void ts_reduce_kernel(const float* __restrict__ feats, float* __restrict__ out) {
    int tg = blockIdx.x * blockDim.x + threadIdx.x;   // 0..2047
    if (tg >= B_DIM * 16) return;
    int b = tg >> 4, f = tg & 15;
    const float* fp = feats + (size_t)b * V_DIM * 16 + f;
    float vals[V_DIM];
    float s = 0.f;
    #pragma unroll
    for (int v = 0; v < V_DIM; v++) { vals[v] = fp[v * 16]; s += vals[v]; }
    float m = s * (1.f / V_DIM);
    float q = 0.f;
    #pragma unroll
    for (int v = 0; v < V_DIM; v++) { float d = vals[v] - m; q += d * d; }
    float sd = sqrtf(q * (1.f / V_DIM));
    out[(size_t)b * 32 + f]      = fminf(fmaxf(m,  -5.f), 5.f);
    out[(size_t)b * 32 + 16 + f] = fminf(fmaxf(sd, -5.f), 5.f);
}

extern "C" void kernel_launch(void* const* d_in, const int* in_sizes, int n_in,
                              void* d_out, int out_size, void* d_ws, size_t ws_size,
                              hipStream_t stream) {
    const float* x = (const float*)d_in[0];
    float* out = (float*)d_out;
    float* feats = (float*)d_ws;   // 4096 series x 16 features = 256 KB

    hipLaunchKernelGGL(ts_feat_kernel, dim3(B_DIM * V_DIM / 2), dim3(NTHREADS), 0, stream,
                       x, feats);
    hipLaunchKernelGGL(ts_reduce_kernel, dim3(8), dim3(NTHREADS), 0, stream,
                       feats, out);
}

// Round 7
// 159.733 us; speedup vs baseline: 1.1709x; 1.1709x over previous
//
#include <hip/hip_runtime.h>
#include <math.h>

#define T_LEN 4096
#define M_LEN 2048   // complex length after real-packing
#define V_DIM 32
#define B_DIM 128
#define NTHREADS 512
#define NWAVES (NTHREADS / 64)   // 8

// insert m into descending triple (a0 >= a1 >= a2)
__device__ __forceinline__ void ins3(float& a0, float& a1, float& a2, float m) {
    if (m > a0) { a2 = a1; a1 = a0; a0 = m; }
    else if (m > a1) { a2 = a1; a1 = m; }
    else if (m > a2) { a2 = m; }
}

template <typename Op>
__device__ __forceinline__ void block_reduce2(float& a, float& b, float* scr, Op op) {
    #pragma unroll
    for (int o = 32; o > 0; o >>= 1) {
        a = op(a, __shfl_down(a, o));
        b = op(b, __shfl_down(b, o));
    }
    int lane = threadIdx.x & 63, w = threadIdx.x >> 6;
    if (lane == 0) { scr[w * 2] = a; scr[w * 2 + 1] = b; }
    __syncthreads();
    if (threadIdx.x == 0) {
        float ra = scr[0], rb = scr[1];
        #pragma unroll
        for (int i = 1; i < NWAVES; i++) { ra = op(ra, scr[i * 2]); rb = op(rb, scr[i * 2 + 1]); }
        scr[2 * NWAVES] = ra; scr[2 * NWAVES + 1] = rb;
    }
    __syncthreads();
    a = scr[2 * NWAVES]; b = scr[2 * NWAVES + 1];
    __syncthreads();
}

// sum-reduce 10 per-thread values across the block; result broadcast to all
__device__ __forceinline__ void block_reduce_sum10(float* v, float* scr) {
    #pragma unroll
    for (int r = 0; r < 10; r++) {
        #pragma unroll
        for (int o = 32; o > 0; o >>= 1) v[r] += __shfl_down(v[r], o);
    }
    int lane = threadIdx.x & 63, w = threadIdx.x >> 6;
    if (lane == 0) {
        #pragma unroll
        for (int r = 0; r < 10; r++) scr[w * 10 + r] = v[r];
    }
    __syncthreads();
    if (threadIdx.x < 10) {
        float s = 0.f;
        #pragma unroll
        for (int i = 0; i < NWAVES; i++) s += scr[i * 10 + threadIdx.x];
        scr[NWAVES * 10 + threadIdx.x] = s;
    }
    __syncthreads();
    #pragma unroll
    for (int r = 0; r < 10; r++) v[r] = scr[NWAVES * 10 + r];
    __syncthreads();
}

__global__ __launch_bounds__(NTHREADS, 8)   // 8 waves/EU -> 32 waves/CU; caps VGPR at 64
void ts_feat_kernel(const float* __restrict__ x, float* __restrict__ feats) {
    __shared__ __align__(16) float data[2][T_LEN];   // 32 KB; also FFT buffer (float2 view)
    __shared__ float scr[128];

    const int tid = threadIdx.x;
    // XCD-aware swizzle: all 16 v-pairs of batch b land on XCD b%8 (assumes
    // round-robin blockIdx->XCD). Bijective over 2048 blocks.
    const int bid  = blockIdx.x;           // 0..2047
    const int xcd  = bid & 7;
    const int idx  = bid >> 3;             // 0..255
    const int b    = xcd + ((idx >> 4) << 3);   // batch 0..127
    const int pair = idx & 15;             // v-pair 0..15
    const int v0   = pair * 2;
    const int sid0 = b * V_DIM + v0;       // series id of si=0

    const float2* __restrict__ p2 =
        reinterpret_cast<const float2*>(x + (size_t)b * T_LEN * V_DIM + v0);

    // ---------- sweep 1: load + sum/min/max ----------
    float s0 = 0.f, s1 = 0.f;
    float mn0 = 3.4e38f, mn1 = 3.4e38f, mx0 = -3.4e38f, mx1 = -3.4e38f;
    #pragma unroll
    for (int i = 0; i < T_LEN / NTHREADS; i++) {
        int t = tid + i * NTHREADS;
        float2 val = p2[(size_t)t * (V_DIM / 2)];
        data[0][t] = val.x; data[1][t] = val.y;
        s0 += val.x; s1 += val.y;
        mn0 = fminf(mn0, val.x); mn1 = fminf(mn1, val.y);
        mx0 = fmaxf(mx0, val.x); mx1 = fmaxf(mx1, val.y);
    }
    __syncthreads();
    block_reduce2(s0, s1, scr, [](float a, float c) { return a + c; });
    block_reduce2(mn0, mn1, scr, [](float a, float c) { return fminf(a, c); });
    block_reduce2(mx0, mx1, scr, [](float a, float c) { return fmaxf(a, c); });

    const float mean0 = s0 * (1.f / T_LEN);
    const float mean1 = s1 * (1.f / T_LEN);

    // ---------- sweep 2: centered moments, slope, ACF (per series) ----------
    // acc: [c2, c3, c4, ctc, lag1..lag6]
    #pragma unroll 1
    for (int si = 0; si < 2; si++) {
        float acc[10];
        #pragma unroll
        for (int r = 0; r < 10; r++) acc[r] = 0.f;
        const float m = si ? mean1 : mean0;
        for (int i = 0; i < T_LEN / NTHREADS; i++) {
            int t = tid + i * NTHREADS;
            float xc = data[si][t] - m;
            float xc2 = xc * xc;
            acc[0] += xc2;
            acc[1] += xc2 * xc;
            acc[2] += xc2 * xc2;
            acc[3] += xc * ((float)t - 2047.5f);
            #pragma unroll
            for (int lag = 1; lag <= 6; lag++) {
                if (t + lag < T_LEN) {
                    acc[3 + lag] += xc * (data[si][t + lag] - m);
                }
            }
        }
        block_reduce_sum10(acc, scr);

        if (tid == 0) {
            const float c2 = acc[0], c3 = acc[1], c4 = acc[2], ct = acc[3];
            float var = c2 * (1.f / T_LEN);
            float sd  = sqrtf(var + 1e-8f);
            float i3  = 1.f / (sd * sd * sd);
            float skew = c3 * (1.f / T_LEN) * i3;
            float kurt = c4 * (1.f / T_LEN) * i3 / sd;
            float slope = ct / 5726622720.f;      // sum(tc^2) = T(T^2-1)/12
            float dn = c2 + 1e-8f;
            float* fp = feats + (size_t)(sid0 + si) * 16;
            fp[0] = m; fp[1] = sd; fp[2] = skew; fp[3] = kurt;
            fp[4] = si ? mn1 : mn0;
            fp[5] = si ? mx1 : mx0;
            fp[6] = slope;
            fp[10] = acc[4] / dn;
            fp[11] = acc[5] / dn;
            fp[12] = acc[6] / dn;
            fp[13] = acc[7] / dn;
            fp[14] = acc[8] / dn;
            fp[15] = acc[9] / dn;
        }
    }

    // ---------- in-place packed-real FFT (radix-2 DIF, M=2048 complex per series) ----------
    float2* Z = reinterpret_cast<float2*>(&data[0][0]);  // series si at Z + si*M_LEN

    for (int s = 10; s >= 0; s--) {
        int half = 1 << s;
        float npih = -3.14159265358979f / (float)half;
        __syncthreads();
        #pragma unroll
        for (int i = 0; i < 2048 / NTHREADS; i++) {
            int bf = tid + i * NTHREADS;        // 0..2047: 1024 butterflies x 2 series
            int si = bf >> 10;
            int q  = bf & 1023;
            int j  = q & (half - 1);
            int i0 = ((q >> s) << (s + 1)) + j + si * M_LEN;
            int i1 = i0 + half;
            float2 a = Z[i0], c = Z[i1];
            float2 sum = make_float2(a.x + c.x, a.y + c.y);
            float2 dif = make_float2(a.x - c.x, a.y - c.y);
            float sn, cs;
            __sincosf(npih * (float)j, &sn, &cs);
            Z[i0] = sum;
            Z[i1] = make_float2(dif.x * cs - dif.y * sn, dif.x * sn + dif.y * cs);
        }
    }
    __syncthreads();

    // ---------- magnitudes (real-unpack) + top-3 ----------
    const float inv_T = 1.f / (float)T_LEN;
    #pragma unroll 1
    for (int si = 0; si < 2; si++) {
        const float2* Zs = Z + si * M_LEN;
        float a0 = -1.f, a1 = -1.f, a2 = -1.f;
        #pragma unroll
        for (int i = 0; i < 2048 / NTHREADS; i++) {
            int k  = 1 + tid + i * NTHREADS;    // 1..2048
            int ka = k & (M_LEN - 1);
            int kb = (M_LEN - k) & (M_LEN - 1);
            float2 Za = Zs[__brev((unsigned)ka) >> 21];
            float2 Zb = Zs[__brev((unsigned)kb) >> 21];
            float Er = 0.5f * (Za.x + Zb.x);
            float Ei = 0.5f * (Za.y - Zb.y);
            float Or = 0.5f * (Za.y + Zb.y);
            float Oi = 0.5f * (Zb.x - Za.x);
            float ang = (float)k * (-3.14159265358979f / (float)M_LEN);
            float sn, cs; __sincosf(ang, &sn, &cs);
            float Xr = Er + cs * Or - sn * Oi;
            float Xi = Ei + cs * Oi + sn * Or;
            float mag = sqrtf(Xr * Xr + Xi * Xi);
            ins3(a0, a1, a2, mag);
        }
        // wave-level merge (lane0 cone uses only valid pulls)
        #pragma unroll
        for (int o = 32; o > 0; o >>= 1) {
            float b0 = __shfl_down(a0, o), b1 = __shfl_down(a1, o), b2 = __shfl_down(a2, o);
            ins3(a0, a1, a2, b0); ins3(a0, a1, a2, b1); ins3(a0, a1, a2, b2);
        }
        int lane = tid & 63, w = tid >> 6;
        if (lane == 0) { scr[w * 3 + 0] = a0; scr[w * 3 + 1] = a1; scr[w * 3 + 2] = a2; }
        __syncthreads();
        if (tid == 0) {
            float t0 = scr[0], t1 = scr[1], t2 = scr[2];
            #pragma unroll
            for (int w2 = 1; w2 < NWAVES; w2++) {
                ins3(t0, t1, t2, scr[w2 * 3 + 0]);
                ins3(t0, t1, t2, scr[w2 * 3 + 1]);
                ins3(t0, t1, t2, scr[w2 * 3 + 2]);
            }
            float* fp = feats + (size_t)(sid0 + si) * 16;
            fp[7] = t0 * inv_T; fp[8] = t1 * inv_T; fp[9] = t2 * inv_T;
        }
        __syncthreads();
    }
}

__global__ void ts_reduce_kernel(const float* __restrict__ feats, float* __restrict__ out) {
    int tg = blockIdx.x * blockDim.x + threadIdx.x;   // 0..2047
    if (tg >= B_DIM * 16) return;
    int b = tg >> 4, f = tg & 15;
    const float* fp = feats + (size_t)b * V_DIM * 16 + f;
    float vals[V_DIM];
    float s = 0.f;
    #pragma unroll
    for (int v = 0; v < V_DIM; v++) { vals[v] = fp[v * 16]; s += vals[v]; }
    float m = s * (1.f / V_DIM);
    float q = 0.f;
    #pragma unroll
    for (int v = 0; v < V_DIM; v++) { float d = vals[v] - m; q += d * d; }
    float sd = sqrtf(q * (1.f / V_DIM));
    out[(size_t)b * 32 + f]      = fminf(fmaxf(m,  -5.f), 5.f);
    out[(size_t)b * 32 + 16 + f] = fminf(fmaxf(sd, -5.f), 5.f);
}

extern "C" void kernel_launch(void* const* d_in, const int* in_sizes, int n_in,
                              void* d_out, int out_size, void* d_ws, size_t ws_size,
                              hipStream_t stream) {
    const float* x = (const float*)d_in[0];
    float* out = (float*)d_out;
    float* feats = (float*)d_ws;   // 4096 series x 16 features = 256 KB

    hipLaunchKernelGGL(ts_feat_kernel, dim3(B_DIM * V_DIM / 2), dim3(NTHREADS), 0, stream,
                       x, feats);
    hipLaunchKernelGGL(ts_reduce_kernel, dim3(8), dim3(256), 0, stream,
                       feats, out);
}

// Round 8
// 155.017 us; speedup vs baseline: 1.2065x; 1.0304x over previous
//
#include <hip/hip_runtime.h>
#include <math.h>

#define T_LEN 4096
#define M_LEN 2048   // complex length after real-packing
#define V_DIM 32
#define B_DIM 128
#define NTHREADS 512
#define NWAVES (NTHREADS / 64)   // 8

// LDS bank swizzle on float2 index: XOR bits 4-6 into bits 1-3.
// Keeps bit 0 -> even/odd f2 pairs stay adjacent (b128-safe, 16B aligned).
__device__ __forceinline__ int SW(int i) { return i ^ (((i >> 4) & 7) << 1); }

// storage position of frequency k after DIF [radix-4 x5, radix-2] (digit reversal)
__device__ __forceinline__ int fpos(int k) {
    return ((k & 3) << 9) | (((k >> 2) & 3) << 7) | (((k >> 4) & 3) << 5)
         | (((k >> 6) & 3) << 3) | (((k >> 8) & 3) << 1) | ((k >> 10) & 1);
}

// insert m into descending triple (a0 >= a1 >= a2)
__device__ __forceinline__ void ins3(float& a0, float& a1, float& a2, float m) {
    if (m > a0) { a2 = a1; a1 = a0; a0 = m; }
    else if (m > a1) { a2 = a1; a1 = m; }
    else if (m > a2) { a2 = m; }
}

template <typename Op>
__device__ __forceinline__ void block_reduce2(float& a, float& b, float* scr, Op op) {
    #pragma unroll
    for (int o = 32; o > 0; o >>= 1) {
        a = op(a, __shfl_down(a, o));
        b = op(b, __shfl_down(b, o));
    }
    int lane = threadIdx.x & 63, w = threadIdx.x >> 6;
    if (lane == 0) { scr[w * 2] = a; scr[w * 2 + 1] = b; }
    __syncthreads();
    if (threadIdx.x == 0) {
        float ra = scr[0], rb = scr[1];
        #pragma unroll
        for (int i = 1; i < NWAVES; i++) { ra = op(ra, scr[i * 2]); rb = op(rb, scr[i * 2 + 1]); }
        scr[2 * NWAVES] = ra; scr[2 * NWAVES + 1] = rb;
    }
    __syncthreads();
    a = scr[2 * NWAVES]; b = scr[2 * NWAVES + 1];
    __syncthreads();
}

// sum-reduce 10 per-thread values across the block; result broadcast to all
__device__ __forceinline__ void block_reduce_sum10(float* v, float* scr) {
    #pragma unroll
    for (int r = 0; r < 10; r++) {
        #pragma unroll
        for (int o = 32; o > 0; o >>= 1) v[r] += __shfl_down(v[r], o);
    }
    int lane = threadIdx.x & 63, w = threadIdx.x >> 6;
    if (lane == 0) {
        #pragma unroll
        for (int r = 0; r < 10; r++) scr[w * 10 + r] = v[r];
    }
    __syncthreads();
    if (threadIdx.x < 10) {
        float s = 0.f;
        #pragma unroll
        for (int i = 0; i < NWAVES; i++) s += scr[i * 10 + threadIdx.x];
        scr[NWAVES * 10 + threadIdx.x] = s;
    }
    __syncthreads();
    #pragma unroll
    for (int r = 0; r < 10; r++) v[r] = scr[NWAVES * 10 + r];
    __syncthreads();
}

__global__ __launch_bounds__(NTHREADS, 8)   // 8 waves/EU; caps VGPR at 64
void ts_feat_kernel(const float* __restrict__ x, float* __restrict__ feats) {
    __shared__ __align__(16) float data[2][T_LEN];   // 32 KB, swizzled packed-complex
    __shared__ float scr[128];
    float* const fd = &data[0][0];
    float2* const Z = reinterpret_cast<float2*>(fd);  // series si at Z + si*2048 (swizzled)

    const int tid = threadIdx.x;
    // XCD-aware swizzle: all 16 v-pairs of batch b land on XCD b%8.
    const int bid  = blockIdx.x;           // 0..2047
    const int xcd  = bid & 7;
    const int idx  = bid >> 3;             // 0..255
    const int b    = xcd + ((idx >> 4) << 3);   // batch 0..127
    const int pair = idx & 15;             // v-pair 0..15
    const int v0   = pair * 2;
    const int sid0 = b * V_DIM + v0;       // series id of si=0

    const float2* __restrict__ p2 =
        reinterpret_cast<const float2*>(x + (size_t)b * T_LEN * V_DIM + v0);

    // ---------- sweep 1: load + sum/min/max; store swizzled ----------
    float s0 = 0.f, s1 = 0.f;
    float mn0 = 3.4e38f, mn1 = 3.4e38f, mx0 = -3.4e38f, mx1 = -3.4e38f;
    const int comp = tid & 1;
    #pragma unroll
    for (int i = 0; i < T_LEN / NTHREADS; i++) {
        int t = tid + i * NTHREADS;
        float2 val = p2[(size_t)t * (V_DIM / 2)];
        int f = SW(t >> 1);
        fd[(f << 1) + comp] = val.x;                 // series 0
        fd[T_LEN + (f << 1) + comp] = val.y;         // series 1
        s0 += val.x; s1 += val.y;
        mn0 = fminf(mn0, val.x); mn1 = fminf(mn1, val.y);
        mx0 = fmaxf(mx0, val.x); mx1 = fmaxf(mx1, val.y);
    }
    __syncthreads();
    block_reduce2(s0, s1, scr, [](float a, float c) { return a + c; });
    block_reduce2(mn0, mn1, scr, [](float a, float c) { return fminf(a, c); });
    block_reduce2(mx0, mx1, scr, [](float a, float c) { return fmaxf(a, c); });

    const float mean0 = s0 * (1.f / T_LEN);
    const float mean1 = s1 * (1.f / T_LEN);

    // ---------- sweep 2: chunked moments, slope, ACF (registers) ----------
    // thread owns floats [8*tid, 8*tid+8); needs 6 boundary floats for lags
    #pragma unroll 1
    for (int si = 0; si < 2; si++) {
        const float m = si ? mean1 : mean0;
        const int fb = (si << 11) + (tid << 2);      // float2 base = si*2048 + 4*tid
        float4 q0 = *reinterpret_cast<const float4*>(&Z[SW(fb)]);
        float4 q1 = *reinterpret_cast<const float4*>(&Z[SW(fb + 2)]);
        float4 q2 = make_float4(0.f, 0.f, 0.f, 0.f);
        float2 q3 = make_float2(0.f, 0.f);
        const bool interior = (tid < NTHREADS - 1);
        if (interior) {
            q2 = *reinterpret_cast<const float4*>(&Z[SW(fb + 4)]);
            q3 = Z[SW(fb + 6)];
        }
        float xc[8] = {q0.x - m, q0.y - m, q0.z - m, q0.w - m,
                       q1.x - m, q1.y - m, q1.z - m, q1.w - m};
        float xb[6];
        if (interior) {
            xb[0] = q2.x - m; xb[1] = q2.y - m; xb[2] = q2.z - m;
            xb[3] = q2.w - m; xb[4] = q3.x - m; xb[5] = q3.y - m;
        } else {
            #pragma unroll
            for (int u = 0; u < 6; u++) xb[u] = 0.f;
        }
        float acc[10];
        #pragma unroll
        for (int r = 0; r < 10; r++) acc[r] = 0.f;
        const float tf0 = (float)(tid * 8) - 2047.5f;
        #pragma unroll
        for (int u = 0; u < 8; u++) {
            float c = xc[u], c2v = c * c;
            acc[0] += c2v;
            acc[1] += c2v * c;
            acc[2] += c2v * c2v;
            acc[3] += c * (tf0 + (float)u);
        }
        #pragma unroll
        for (int L = 1; L <= 6; L++) {
            #pragma unroll
            for (int u = 0; u < 8; u++) {
                float nx = (u + L < 8) ? xc[u + L] : xb[u + L - 8];
                acc[3 + L] += xc[u] * nx;
            }
        }
        block_reduce_sum10(acc, scr);

        if (tid == 0) {
            const float c2 = acc[0], c3 = acc[1], c4 = acc[2], ct = acc[3];
            float var = c2 * (1.f / T_LEN);
            float sd  = sqrtf(var + 1e-8f);
            float i3  = 1.f / (sd * sd * sd);
            float skew = c3 * (1.f / T_LEN) * i3;
            float kurt = c4 * (1.f / T_LEN) * i3 / sd;
            float slope = ct / 5726622720.f;      // sum(tc^2) = T(T^2-1)/12
            float dn = c2 + 1e-8f;
            float* fp = feats + (size_t)(sid0 + si) * 16;
            fp[0] = m; fp[1] = sd; fp[2] = skew; fp[3] = kurt;
            fp[4] = si ? mn1 : mn0;
            fp[5] = si ? mx1 : mx0;
            fp[6] = slope;
            fp[10] = acc[4] / dn;
            fp[11] = acc[5] / dn;
            fp[12] = acc[6] / dn;
            fp[13] = acc[7] / dn;
            fp[14] = acc[8] / dn;
            fp[15] = acc[9] / dn;
        }
    }

    // ---------- in-place packed-real FFT: 5 radix-4 DIF stages + 1 radix-2 ----------
    // M=2048 complex per series. W_N = e^{-2pi i/N}.
    #pragma unroll
    for (int st = 0; st < 5; st++) {
        const int lq = 9 - 2 * st;               // log2(quarter)
        const int q  = 1 << lq;                  // span = 4q
        const float scale = -3.06796158e-3f * (float)(1 << (2 * st)); // -2pi/2048 * 4^st
        __syncthreads();
        #pragma unroll
        for (int si = 0; si < 2; si++) {
            const int w = tid;                   // 512 butterflies per series per stage
            const int g = w >> lq;
            const int j = w & (q - 1);
            const int base = (si << 11) + (g << (lq + 2)) + j;
            const int p0 = SW(base), p1 = SW(base + q);
            const int p2i = SW(base + 2 * q), p3 = SW(base + 3 * q);
            float2 a = Z[p0], bb = Z[p1], c = Z[p2i], d = Z[p3];
            float t0r = a.x + c.x,  t0i = a.y + c.y;
            float t1r = a.x - c.x,  t1i = a.y - c.y;
            float t2r = bb.x + d.x, t2i = bb.y + d.y;
            float t3r = bb.x - d.x, t3i = bb.y - d.y;
            float sn, cs;
            __sincosf(scale * (float)j, &sn, &cs);
            float c2 = cs * cs - sn * sn, s2 = 2.f * cs * sn;     // W^2j
            float c3 = c2 * cs - s2 * sn, s3 = c2 * sn + s2 * cs; // W^3j
            float y1r = t1r + t3i, y1i = t1i - t3r;   // (a - i b - c + i d)
            float y2r = t0r - t2r, y2i = t0i - t2i;
            float y3r = t1r - t3i, y3i = t1i + t3r;
            Z[p0]  = make_float2(t0r + t2r, t0i + t2i);
            Z[p1]  = make_float2(y1r * cs - y1i * sn, y1r * sn + y1i * cs);
            Z[p2i] = make_float2(y2r * c2 - y2i * s2, y2r * s2 + y2i * c2);
            Z[p3]  = make_float2(y3r * c3 - y3i * s3, y3r * s3 + y3i * c3);
        }
    }
    // radix-2 final stage (span 2): twiddle-free, b128 read/write
    __syncthreads();
    #pragma unroll
    for (int bfI = 0; bfI < 4; bfI++) {
        int mI = tid + (bfI << 9);               // 0..2047
        int si = mI >> 10, g = mI & 1023;
        int p = SW((si << 11) + (g << 1));       // even -> pair adjacent
        float4 ab = *reinterpret_cast<float4*>(&Z[p]);
        float4 o;
        o.x = ab.x + ab.z; o.y = ab.y + ab.w;
        o.z = ab.x - ab.z; o.w = ab.y - ab.w;
        *reinterpret_cast<float4*>(&Z[p]) = o;
    }
    __syncthreads();

    // ---------- magnitudes (real-unpack) + top-3 ----------
    const float inv_T = 1.f / (float)T_LEN;
    #pragma unroll 1
    for (int si = 0; si < 2; si++) {
        const int zb = si << 11;
        float a0 = -1.f, a1 = -1.f, a2 = -1.f;
        #pragma unroll
        for (int i = 0; i < M_LEN / NTHREADS; i++) {
            int k  = 1 + tid + i * NTHREADS;     // 1..2048
            int ka = k & (M_LEN - 1);
            int kb = (M_LEN - k) & (M_LEN - 1);
            float2 Za = Z[zb + SW(fpos(ka))];
            float2 Zb = Z[zb + SW(fpos(kb))];
            float Er = 0.5f * (Za.x + Zb.x);
            float Ei = 0.5f * (Za.y - Zb.y);
            float Or = 0.5f * (Za.y + Zb.y);
            float Oi = 0.5f * (Zb.x - Za.x);
            float ang = (float)k * (-3.14159265358979f / (float)M_LEN);
            float sn, cs; __sincosf(ang, &sn, &cs);
            float Xr = Er + cs * Or - sn * Oi;
            float Xi = Ei + cs * Oi + sn * Or;
            float mag = sqrtf(Xr * Xr + Xi * Xi);
            ins3(a0, a1, a2, mag);
        }
        // wave-level merge
        #pragma unroll
        for (int o = 32; o > 0; o >>= 1) {
            float b0 = __shfl_down(a0, o), b1 = __shfl_down(a1, o), b2 = __shfl_down(a2, o);
            ins3(a0, a1, a2, b0); ins3(a0, a1, a2, b1); ins3(a0, a1, a2, b2);
        }
        int lane = tid & 63, w = tid >> 6;
        if (lane == 0) { scr[w * 3 + 0] = a0; scr[w * 3 + 1] = a1; scr[w * 3 + 2] = a2; }
        __syncthreads();
        if (tid == 0) {
            float t0 = scr[0], t1 = scr[1], t2 = scr[2];
            #pragma unroll
            for (int w2 = 1; w2 < NWAVES; w2++) {
                ins3(t0, t1, t2, scr[w2 * 3 + 0]);
                ins3(t0, t1, t2, scr[w2 * 3 + 1]);
                ins3(t0, t1, t2, scr[w2 * 3 + 2]);
            }
            float* fp = feats + (size_t)(sid0 + si) * 16;
            fp[7] = t0 * inv_T; fp[8] = t1 * inv_T; fp[9] = t2 * inv_T;
        }
        __syncthreads();
    }
}

__global__ void ts_reduce_kernel(const float* __restrict__ feats, float* __restrict__ out) {
    int tg = blockIdx.x * blockDim.x + threadIdx.x;   // 0..2047
    if (tg >= B_DIM * 16) return;
    int b = tg >> 4, f = tg & 15;
    const float* fp = feats + (size_t)b * V_DIM * 16 + f;
    float vals[V_DIM];
    float s = 0.f;
    #pragma unroll
    for (int v = 0; v < V_DIM; v++) { vals[v] = fp[v * 16]; s += vals[v]; }
    float m = s * (1.f / V_DIM);
    float q = 0.f;
    #pragma unroll
    for (int v = 0; v < V_DIM; v++) { float d = vals[v] - m; q += d * d; }
    float sd = sqrtf(q * (1.f / V_DIM));
    out[(size_t)b * 32 + f]      = fminf(fmaxf(m,  -5.f), 5.f);
    out[(size_t)b * 32 + 16 + f] = fminf(fmaxf(sd, -5.f), 5.f);
}

extern "C" void kernel_launch(void* const* d_in, const int* in_sizes, int n_in,
                              void* d_out, int out_size, void* d_ws, size_t ws_size,
                              hipStream_t stream) {
    const float* x = (const float*)d_in[0];
    float* out = (float*)d_out;
    float* feats = (float*)d_ws;   // 4096 series x 16 features = 256 KB

    hipLaunchKernelGGL(ts_feat_kernel, dim3(B_DIM * V_DIM / 2), dim3(NTHREADS), 0, stream,
                       x, feats);
    hipLaunchKernelGGL(ts_reduce_kernel, dim3(8), dim3(256), 0, stream,
                       feats, out);
}

// Round 9
// 147.229 us; speedup vs baseline: 1.2704x; 1.0529x over previous
//
#include <hip/hip_runtime.h>
#include <math.h>

#define T_LEN 4096
#define M_LEN 2048   // complex length after real-packing
#define V_DIM 32
#define B_DIM 128
#define NTHREADS 512
#define NWAVES 8

// LDS bank swizzle on float2 index: XOR bits 4-6 into bits 1-3.
// Preserves bit 0 -> even/odd f2 pairs stay adjacent (b128-safe, 16B aligned).
__device__ __forceinline__ int SW(int i) { return i ^ (((i >> 4) & 7) << 1); }

// storage position of frequency k after DIF [radix-4 x5, radix-2] (digit reversal)
__device__ __forceinline__ int fpos(int k) {
    return ((k & 3) << 9) | (((k >> 2) & 3) << 7) | (((k >> 4) & 3) << 5)
         | (((k >> 6) & 3) << 3) | (((k >> 8) & 3) << 1) | ((k >> 10) & 1);
}

// insert m into descending triple (a0 >= a1 >= a2)
__device__ __forceinline__ void ins3(float& a0, float& a1, float& a2, float m) {
    if (m > a0) { a2 = a1; a1 = a0; a0 = m; }
    else if (m > a1) { a2 = a1; a1 = m; }
    else if (m > a2) { a2 = m; }
}

// scr float regions
#define SCR_A_PART 0     // 8 waves x 6
#define SCR_A_FIN  48    // 6: [sum0,sum1,mn0,mn1,mx0,mx1]
#define SCR_B_PART 64    // 2 series x 8 waves x 4 lanes x 10
#define SCR_B_FIN  704   // 2 x 10
#define SCR_C_PART 724   // 8 waves x 6
#define SCR_SIZE   772

// radix-4 DIF stage, in place, swizzled addressing. W = e^{-2pi i/2048}.
template <int ST>
__device__ __forceinline__ void fft_stage(float2* Z, int tid) {
    constexpr int lq = 9 - 2 * ST;           // log2(quarter)
    constexpr int q  = 1 << lq;
    const float scale = -3.06796158e-3f * (float)(1 << (2 * ST)); // -2pi/2048 * 4^ST
    #pragma unroll
    for (int si = 0; si < 2; si++) {
        const int g = tid >> lq;
        const int j = tid & (q - 1);
        const int base = (si << 11) + (g << (lq + 2)) + j;
        const int p0 = SW(base), p1 = SW(base + q);
        const int p2i = SW(base + 2 * q), p3 = SW(base + 3 * q);
        float2 a = Z[p0], bb = Z[p1], c = Z[p2i], d = Z[p3];
        float t0r = a.x + c.x,  t0i = a.y + c.y;
        float t1r = a.x - c.x,  t1i = a.y - c.y;
        float t2r = bb.x + d.x, t2i = bb.y + d.y;
        float t3r = bb.x - d.x, t3i = bb.y - d.y;
        float sn, cs;
        __sincosf(scale * (float)j, &sn, &cs);
        float c2 = cs * cs - sn * sn, s2 = 2.f * cs * sn;     // W^2j
        float c3 = c2 * cs - s2 * sn, s3 = c2 * sn + s2 * cs; // W^3j
        float y1r = t1r + t3i, y1i = t1i - t3r;
        float y2r = t0r - t2r, y2i = t0i - t2i;
        float y3r = t1r - t3i, y3i = t1i + t3r;
        Z[p0]  = make_float2(t0r + t2r, t0i + t2i);
        Z[p1]  = make_float2(y1r * cs - y1i * sn, y1r * sn + y1i * cs);
        Z[p2i] = make_float2(y2r * c2 - y2i * s2, y2r * s2 + y2i * c2);
        Z[p3]  = make_float2(y3r * c3 - y3i * s3, y3r * s3 + y3i * c3);
    }
}

// post-radix2 value at logical position p (radix-2 stage fused: pair add/sub)
__device__ __forceinline__ float2 rdpost(const float2* Z, int zb, int p) {
    int e = p & ~1;
    float4 v = *reinterpret_cast<const float4*>(&Z[zb + SW(e)]);
    return (p & 1) ? make_float2(v.x - v.z, v.y - v.w)
                   : make_float2(v.x + v.z, v.y + v.w);
}

__global__ __launch_bounds__(NTHREADS, 8)
void ts_feat_kernel(const float* __restrict__ x, float* __restrict__ feats) {
    __shared__ __align__(16) float data[2][T_LEN];   // 32 KB swizzled packed-complex
    __shared__ float scr[SCR_SIZE];
    float* const fd = &data[0][0];
    float2* const Z = reinterpret_cast<float2*>(fd);

    const int tid = threadIdx.x;
    // XCD-aware swizzle: all 16 v-pairs of batch b land on XCD b%8.
    const int bid  = blockIdx.x;           // 0..2047
    const int xcd  = bid & 7;
    const int idx  = bid >> 3;
    const int b    = xcd + ((idx >> 4) << 3);
    const int pair = idx & 15;
    const int v0   = pair * 2;
    const int sid0 = b * V_DIM + v0;

    const float2* __restrict__ p2 =
        reinterpret_cast<const float2*>(x + (size_t)b * T_LEN * V_DIM + v0);

    // ---------- sweep 1: load + sum/min/max; store swizzled ----------
    float s0 = 0.f, s1 = 0.f;
    float mn0 = 3.4e38f, mn1 = 3.4e38f, mx0 = -3.4e38f, mx1 = -3.4e38f;
    const int comp = tid & 1;
    #pragma unroll
    for (int i = 0; i < 8; i++) {
        int t = tid + i * NTHREADS;
        float2 val = p2[(size_t)t * (V_DIM / 2)];
        int f = SW(t >> 1);
        fd[(f << 1) + comp] = val.x;
        fd[T_LEN + (f << 1) + comp] = val.y;
        s0 += val.x; s1 += val.y;
        mn0 = fminf(mn0, val.x); mn1 = fminf(mn1, val.y);
        mx0 = fmaxf(mx0, val.x); mx1 = fmaxf(mx1, val.y);
    }
    #pragma unroll
    for (int o = 32; o > 0; o >>= 1) {
        s0 += __shfl_down(s0, o); s1 += __shfl_down(s1, o);
        mn0 = fminf(mn0, __shfl_down(mn0, o)); mn1 = fminf(mn1, __shfl_down(mn1, o));
        mx0 = fmaxf(mx0, __shfl_down(mx0, o)); mx1 = fmaxf(mx1, __shfl_down(mx1, o));
    }
    const int lane = tid & 63, wv = tid >> 6;
    if (lane == 0) {
        float* p = &scr[SCR_A_PART + wv * 6];
        p[0] = s0; p[1] = s1; p[2] = mn0; p[3] = mn1; p[4] = mx0; p[5] = mx1;
    }
    __syncthreads();                                     // sync 1
    if (tid < 6) {
        float r = scr[SCR_A_PART + tid];
        #pragma unroll
        for (int w = 1; w < NWAVES; w++) {
            float v = scr[SCR_A_PART + w * 6 + tid];
            r = (tid < 2) ? (r + v) : ((tid < 4) ? fminf(r, v) : fmaxf(r, v));
        }
        scr[SCR_A_FIN + tid] = r;
    }
    __syncthreads();                                     // sync 2
    const float mean0 = scr[SCR_A_FIN + 0] * (1.f / T_LEN);
    const float mean1 = scr[SCR_A_FIN + 1] * (1.f / T_LEN);
    float fmn = 0.f, fmx = 0.f;
    if (tid < 2) { fmn = scr[SCR_A_FIN + 2 + tid]; fmx = scr[SCR_A_FIN + 4 + tid]; }

    // ---------- sweep 2: streaming moments/slope/ACF (sliding window) ----------
    #pragma unroll 1
    for (int si = 0; si < 2; si++) {
        const float m = si ? mean1 : mean0;
        const int fb = (si << 11) + (tid << 2);          // float2 base
        float4 q0 = *reinterpret_cast<const float4*>(&Z[SW(fb)]);
        float4 q1 = *reinterpret_cast<const float4*>(&Z[SW(fb + 2)]);
        float p1v = 0.f, p2v = 0.f, p3v = 0.f, p4v = 0.f, p5v = 0.f, p6v = 0.f;
        if (tid > 0) {                                   // prev-chunk tail x[8t-6..8t-1]
            float2 tv = Z[SW(fb - 3)];
            float4 tq = *reinterpret_cast<const float4*>(&Z[SW(fb - 2)]);
            p6v = tv.x - m; p5v = tv.y - m;
            p4v = tq.x - m; p3v = tq.y - m; p2v = tq.z - m; p1v = tq.w - m;
        }
        float acc[10];
        #pragma unroll
        for (int r = 0; r < 10; r++) acc[r] = 0.f;
        const float tf0 = (float)(tid * 8) - 2047.5f;
        float xs[8] = {q0.x, q0.y, q0.z, q0.w, q1.x, q1.y, q1.z, q1.w};
        #pragma unroll
        for (int u = 0; u < 8; u++) {
            float c = xs[u] - m;
            float c2v = c * c;
            acc[0] += c2v;
            acc[1] += c2v * c;
            acc[2] += c2v * c2v;
            acc[3] += c * (tf0 + (float)u);
            acc[4] += p1v * c; acc[5] += p2v * c; acc[6] += p3v * c;
            acc[7] += p4v * c; acc[8] += p5v * c; acc[9] += p6v * c;
            p6v = p5v; p5v = p4v; p4v = p3v; p3v = p2v; p2v = p1v; p1v = c;
        }
        // wave reduce to 4 lanes (rounds 32,16,8,4), lanes 0-3 write partials
        #pragma unroll
        for (int r = 0; r < 10; r++) {
            acc[r] += __shfl_down(acc[r], 32);
            acc[r] += __shfl_down(acc[r], 16);
            acc[r] += __shfl_down(acc[r], 8);
            acc[r] += __shfl_down(acc[r], 4);
        }
        if (lane < 4) {
            #pragma unroll
            for (int r = 0; r < 10; r++)
                scr[SCR_B_PART + si * 320 + wv * 40 + lane * 10 + r] = acc[r];
        }
    }
    __syncthreads();                                     // sync 3

    // ---------- B finalize overlapped with FFT stage 0 ----------
    if (tid < 10) {
        float s = 0.f;
        #pragma unroll
        for (int e = 0; e < 32; e++) s += scr[SCR_B_PART + e * 10 + tid];
        scr[SCR_B_FIN + tid] = s;
    } else if (tid >= 16 && tid < 26) {
        const int f = tid - 16;
        float s = 0.f;
        #pragma unroll
        for (int e = 0; e < 32; e++) s += scr[SCR_B_PART + 320 + e * 10 + f];
        scr[SCR_B_FIN + 10 + f] = s;
    }
    fft_stage<0>(Z, tid);
    __syncthreads();                                     // sync 4

    // feats base features by tid 0/1, overlapped with FFT stage 1
    if (tid < 2) {
        const float* A = &scr[SCR_B_FIN + tid * 10];
        const float m = tid ? mean1 : mean0;
        float c2 = A[0], c3 = A[1], c4 = A[2], ct = A[3];
        float var = c2 * (1.f / T_LEN);
        float sd  = sqrtf(var + 1e-8f);
        float i3  = 1.f / (sd * sd * sd);
        float dn  = c2 + 1e-8f;
        float* fp = feats + (size_t)(sid0 + tid) * 16;
        fp[0] = m; fp[1] = sd;
        fp[2] = c3 * (1.f / T_LEN) * i3;
        fp[3] = c4 * (1.f / T_LEN) * i3 / sd;
        fp[4] = fmn; fp[5] = fmx;
        fp[6] = ct / 5726622720.f;                       // sum(tc^2) = T(T^2-1)/12
        fp[10] = A[4] / dn; fp[11] = A[5] / dn; fp[12] = A[6] / dn;
        fp[13] = A[7] / dn; fp[14] = A[8] / dn; fp[15] = A[9] / dn;
    }
    fft_stage<1>(Z, tid);
    __syncthreads();                                     // sync 5
    fft_stage<2>(Z, tid);
    __syncthreads();                                     // sync 6
    fft_stage<3>(Z, tid);
    __syncthreads();                                     // sync 7
    fft_stage<4>(Z, tid);
    __syncthreads();                                     // sync 8

    // ---------- magnitudes (radix-2 fused + real-unpack), both series ----------
    const float inv_T = 1.f / (float)T_LEN;
    float a0 = -1.f, a1 = -1.f, a2 = -1.f;               // series 0 top-3
    float b0 = -1.f, b1 = -1.f, b2 = -1.f;               // series 1 top-3
    #pragma unroll
    for (int i = 0; i < 4; i++) {
        int k  = 1 + tid + i * NTHREADS;                 // 1..2048
        int ka = k & (M_LEN - 1);
        int kb = (M_LEN - k) & (M_LEN - 1);
        int pa = fpos(ka), pb = fpos(kb);
        float ang = (float)k * (-3.14159265358979f / (float)M_LEN);
        float sn, cs; __sincosf(ang, &sn, &cs);
        {
            float2 Za = rdpost(Z, 0, pa), Zb = rdpost(Z, 0, pb);
            float Er = 0.5f * (Za.x + Zb.x), Ei = 0.5f * (Za.y - Zb.y);
            float Or = 0.5f * (Za.y + Zb.y), Oi = 0.5f * (Zb.x - Za.x);
            float Xr = Er + cs * Or - sn * Oi;
            float Xi = Ei + cs * Oi + sn * Or;
            ins3(a0, a1, a2, sqrtf(Xr * Xr + Xi * Xi));
        }
        {
            float2 Za = rdpost(Z, M_LEN, pa), Zb = rdpost(Z, M_LEN, pb);
            float Er = 0.5f * (Za.x + Zb.x), Ei = 0.5f * (Za.y - Zb.y);
            float Or = 0.5f * (Za.y + Zb.y), Oi = 0.5f * (Zb.x - Za.x);
            float Xr = Er + cs * Or - sn * Oi;
            float Xi = Ei + cs * Oi + sn * Or;
            ins3(b0, b1, b2, sqrtf(Xr * Xr + Xi * Xi));
        }
    }
    #pragma unroll
    for (int o = 32; o > 0; o >>= 1) {
        float u0 = __shfl_down(a0, o), u1 = __shfl_down(a1, o), u2 = __shfl_down(a2, o);
        ins3(a0, a1, a2, u0); ins3(a0, a1, a2, u1); ins3(a0, a1, a2, u2);
        float w0 = __shfl_down(b0, o), w1 = __shfl_down(b1, o), w2 = __shfl_down(b2, o);
        ins3(b0, b1, b2, w0); ins3(b0, b1, b2, w1); ins3(b0, b1, b2, w2);
    }
    if (lane == 0) {
        float* p = &scr[SCR_C_PART + wv * 6];
        p[0] = a0; p[1] = a1; p[2] = a2; p[3] = b0; p[4] = b1; p[5] = b2;
    }
    __syncthreads();                                     // sync 9
    if (tid < 2) {
        const int off = SCR_C_PART + tid * 3;
        float t0 = scr[off], t1 = scr[off + 1], t2 = scr[off + 2];
        #pragma unroll
        for (int w = 1; w < NWAVES; w++) {
            ins3(t0, t1, t2, scr[off + w * 6]);
            ins3(t0, t1, t2, scr[off + w * 6 + 1]);
            ins3(t0, t1, t2, scr[off + w * 6 + 2]);
        }
        float* fp = feats + (size_t)(sid0 + tid) * 16;
        fp[7] = t0 * inv_T; fp[8] = t1 * inv_T; fp[9] = t2 * inv_T;
    }
}

__global__ void ts_reduce_kernel(const float* __restrict__ feats, float* __restrict__ out) {
    int tg = blockIdx.x * blockDim.x + threadIdx.x;   // 0..2047
    if (tg >= B_DIM * 16) return;
    int b = tg >> 4, f = tg & 15;
    const float* fp = feats + (size_t)b * V_DIM * 16 + f;
    float vals[V_DIM];
    float s = 0.f;
    #pragma unroll
    for (int v = 0; v < V_DIM; v++) { vals[v] = fp[v * 16]; s += vals[v]; }
    float m = s * (1.f / V_DIM);
    float q = 0.f;
    #pragma unroll
    for (int v = 0; v < V_DIM; v++) { float d = vals[v] - m; q += d * d; }
    float sd = sqrtf(q * (1.f / V_DIM));
    out[(size_t)b * 32 + f]      = fminf(fmaxf(m,  -5.f), 5.f);
    out[(size_t)b * 32 + 16 + f] = fminf(fmaxf(sd, -5.f), 5.f);
}

extern "C" void kernel_launch(void* const* d_in, const int* in_sizes, int n_in,
                              void* d_out, int out_size, void* d_ws, size_t ws_size,
                              hipStream_t stream) {
    const float* x = (const float*)d_in[0];
    float* out = (float*)d_out;
    float* feats = (float*)d_ws;   // 4096 series x 16 features = 256 KB

    hipLaunchKernelGGL(ts_feat_kernel, dim3(B_DIM * V_DIM / 2), dim3(NTHREADS), 0, stream,
                       x, feats);
    hipLaunchKernelGGL(ts_reduce_kernel, dim3(8), dim3(256), 0, stream,
                       feats, out);
}